// Round 8
// baseline (298.346 us; speedup 1.0000x reference)
//
#include <hip/hip_runtime.h>

#define NV 100000
#define NC 50000
#define DVAR 8
#define DCON 16

using short8 = __attribute__((ext_vector_type(8))) short;
using f32x4  = __attribute__((ext_vector_type(4))) float;

typedef const __attribute__((address_space(1))) void* as1cv;
typedef __attribute__((address_space(3))) void* as3v;

__device__ __forceinline__ unsigned short f2bf(float f) {
    union { float f; unsigned int u; } v; v.f = f;
    return (unsigned short)((v.u + 0x7fffu + ((v.u >> 16) & 1u)) >> 16);  // RNE
}
__device__ __forceinline__ float bflo(unsigned int u) {
    union { unsigned int u; float f; } v; v.u = u << 16; return v.f;
}
__device__ __forceinline__ float bfhi(unsigned int u) {
    union { unsigned int u; float f; } v; v.u = u & 0xffff0000u; return v.f;
}

// ---------------------------------------------------------------- pack W into MFMA B-fragment
__global__ __launch_bounds__(256) void pack_kernel(
    const float* __restrict__ Wvar, const float* __restrict__ Wcon,
    const float* __restrict__ Wiv,  const float* __restrict__ Wic,
    unsigned short* __restrict__ WbVar, unsigned short* __restrict__ WbCon,
    unsigned short* __restrict__ WbIv,  unsigned short* __restrict__ WbIc,
    float* __restrict__ S)
{
    const int tid = blockIdx.x * 256 + threadIdx.x;
    for (int i = tid; i < 9 * 128 * 32; i += gridDim.x * 256) {
        int s = i >> 12, rem = i & 4095, c = rem >> 5, k = rem & 31;
        int src = (s * 32 + k) * 128 + c;
        WbVar[i] = f2bf(Wvar[src]);
        WbCon[i] = f2bf(Wcon[src]);
    }
    for (int i = tid; i < 128 * 32; i += gridDim.x * 256) {
        int c = i >> 5, k = i & 31;
        int src = k * 128 + c;
        WbIv[i] = f2bf(Wiv[src]);
        WbIc[i] = f2bf(Wic[src]);
    }
    if (tid == 0) S[0] = 0.f;
}

// ---------------------------------------------------------------- init: h = bf16(x) @ W + b
__global__ __launch_bounds__(256) void init_mfma(
    const float* __restrict__ x,          // M x 32 (pre-offset)
    const unsigned short* __restrict__ Wb,
    const float* __restrict__ bias,
    unsigned short* __restrict__ hout, int M)
{
    const int t = threadIdx.x;
    const int lane = t & 63;
    const int w = t >> 6;
    const int lrow = lane & 15;
    const int lg = lane >> 4;
    const int wrow0 = blockIdx.x * 64 + w * 16;
    int arow = wrow0 + lrow;
    int arowc = arow < M ? arow : M - 1;

    const float4* xp = (const float4*)(x + (size_t)arowc * 32 + lg * 8);
    float4 xa = xp[0], xb = xp[1];
    short8 afr;
    afr[0] = (short)f2bf(xa.x); afr[1] = (short)f2bf(xa.y);
    afr[2] = (short)f2bf(xa.z); afr[3] = (short)f2bf(xa.w);
    afr[4] = (short)f2bf(xb.x); afr[5] = (short)f2bf(xb.y);
    afr[6] = (short)f2bf(xb.z); afr[7] = (short)f2bf(xb.w);

    #pragma unroll
    for (int ct = 0; ct < 8; ++ct) {
        int c = ct * 16 + lrow;
        short8 bfr = *(const short8*)(Wb + (size_t)c * 32 + lg * 8);
        f32x4 acc = {0.f, 0.f, 0.f, 0.f};
        acc = __builtin_amdgcn_mfma_f32_16x16x32_bf16(afr, bfr, acc, 0, 0, 0);
        float bv = bias[c];
        #pragma unroll
        for (int r = 0; r < 4; ++r) {
            int orow = wrow0 + lg * 4 + r;
            if (orow < M) hout[(size_t)orow * 128 + c] = f2bf(acc[r] + bv);
        }
    }
}

// ---------------------------------------------------------------- gather-sum (bf16, coalesced)
template<int DEG>
__global__ __launch_bounds__(256) void agg_bf16(
    const unsigned short* __restrict__ hnb, const int* __restrict__ idx,
    unsigned short* __restrict__ agg, int M)
{
    const int tid = blockIdx.x * 256 + threadIdx.x;
    const int row = tid >> 4;
    const int part = tid & 15;
    if (row >= M) return;
    int nb[DEG];
    #pragma unroll
    for (int d4 = 0; d4 < DEG / 4; ++d4)
        *(int4*)(&nb[d4 * 4]) = *(const int4*)(idx + (size_t)row * DEG + d4 * 4);
    float a0=0.f,a1=0.f,a2=0.f,a3=0.f,a4=0.f,a5=0.f,a6=0.f,a7=0.f;
    #pragma unroll
    for (int b = 0; b < DEG; b += 8) {
        uint4 q[8];
        #pragma unroll
        for (int j = 0; j < 8; ++j)
            q[j] = *(const uint4*)(hnb + (size_t)nb[b + j] * 128 + part * 8);
        #pragma unroll
        for (int j = 0; j < 8; ++j) {
            a0 += bflo(q[j].x); a1 += bfhi(q[j].x);
            a2 += bflo(q[j].y); a3 += bfhi(q[j].y);
            a4 += bflo(q[j].z); a5 += bfhi(q[j].z);
            a6 += bflo(q[j].w); a7 += bfhi(q[j].w);
        }
    }
    uint4 o;
    o.x = (unsigned)f2bf(a0) | ((unsigned)f2bf(a1) << 16);
    o.y = (unsigned)f2bf(a2) | ((unsigned)f2bf(a3) << 16);
    o.z = (unsigned)f2bf(a4) | ((unsigned)f2bf(a5) << 16);
    o.w = (unsigned)f2bf(a6) | ((unsigned)f2bf(a7) << 16);
    *(uint4*)(agg + (size_t)row * 128 + part * 8) = o;
}

// ---------------------------------------------------------------- LDS-staged MFMA layer:
// h_out = [agg | h_self | x_self] @ W + b   (K = 288 = 9 steps)
// A-tiles staged 64x128 bf16 via global_load_lds with chunk-XOR swizzle (inverse-swz source).
// FINAL: emit dot1[row] = h·Wq[128:] per row and atomicAdd S += Σ h·Wq[:128].
template<bool FINAL>
__global__ __launch_bounds__(256, 2) void gemm_mfma(
    const unsigned short* hself,      // may alias hout (in-place v-update)
    const unsigned short* __restrict__ aggin,
    const float* __restrict__ xself,
    const unsigned short* __restrict__ Wb,
    const float* __restrict__ bias,
    unsigned short* hout,
    const float* __restrict__ Wq, float* __restrict__ S, float* __restrict__ dotout,
    int M)
{
    __shared__ __align__(16) unsigned short Aagg[64 * 128];
    __shared__ __align__(16) unsigned short Aself[64 * 128];
    __shared__ float red[4];
    const int t = threadIdx.x;
    const int lane = t & 63;
    const int w = t >> 6;
    const int lrow = lane & 15;
    const int lg = lane >> 4;
    const int r0 = blockIdx.x * 64;
    const int wrow0 = r0 + w * 16;
    const int arow = wrow0 + lrow;
    const int arowc = arow < M ? arow : M - 1;

    // x-fragment to registers (issued first; independent)
    short8 xfr;
    {
        const float4* xp = (const float4*)(xself + (size_t)arowc * 32 + lg * 8);
        float4 xa = xp[0], xb = xp[1];
        xfr[0] = (short)f2bf(xa.x); xfr[1] = (short)f2bf(xa.y);
        xfr[2] = (short)f2bf(xa.z); xfr[3] = (short)f2bf(xa.w);
        xfr[4] = (short)f2bf(xb.x); xfr[5] = (short)f2bf(xb.y);
        xfr[6] = (short)f2bf(xb.z); xfr[7] = (short)f2bf(xb.w);
    }

    // ---- async staging: 64 rows x 128 cols of agg and hself into LDS.
    // LDS chunk L (16B) holds global (row = L>>4, chunk c^(row&7)) — inverse-swizzled source,
    // linear LDS dest (global_load_lds writes base + lane*16).
    #pragma unroll
    for (int i = 0; i < 4; ++i) {
        int L = i * 256 + t;
        int row = L >> 4, c = L & 15;
        int gr = r0 + row;
        int grc = gr < M ? gr : M - 1;
        int cs = c ^ (row & 7);
        __builtin_amdgcn_global_load_lds(
            (as1cv)(aggin + (size_t)grc * 128 + cs * 8),
            (as3v)(&Aagg[(size_t)L * 8]), 16, 0, 0);
        __builtin_amdgcn_global_load_lds(
            (as1cv)(hself + (size_t)grc * 128 + cs * 8),
            (as3v)(&Aself[(size_t)L * 8]), 16, 0, 0);
    }

    // prefetch B for step 0 (drained by the barrier too)
    short8 bfr[2][8];
    #pragma unroll
    for (int ct = 0; ct < 8; ++ct)
        bfr[0][ct] = *(const short8*)(Wb + (size_t)(ct * 16 + lrow) * 32 + lg * 8);

    __syncthreads();   // drains vmcnt(0): staging + bfr[0] complete

    // swizzled LDS A-fragment read: row (w*16+lrow), chunk (4s+lg)^(lrow&7)
    auto ldsA = [&](const unsigned short* base, int srel) -> short8 {
        int chunk = (4 * srel + lg) ^ (lrow & 7);
        return *(const short8*)(base + ((size_t)(w * 16 + lrow) * 16 + chunk) * 8);
    };

    f32x4 acc[8];
    #pragma unroll
    for (int ct = 0; ct < 8; ++ct) acc[ct] = (f32x4){0.f, 0.f, 0.f, 0.f};

    short8 afr = ldsA(Aagg, 0);
    #pragma unroll
    for (int s = 0; s < 9; ++s) {
        const int cur = s & 1, nxt = cur ^ 1;
        short8 afr_nxt;
        if (s < 8) {
            #pragma unroll
            for (int ct = 0; ct < 8; ++ct)
                bfr[nxt][ct] = *(const short8*)(
                    Wb + ((size_t)(s + 1) * 128 + ct * 16 + lrow) * 32 + lg * 8);
            afr_nxt = (s + 1 < 4) ? ldsA(Aagg, s + 1)
                    : (s + 1 < 8) ? ldsA(Aself, s + 1 - 4)
                                  : xfr;
        }
        #pragma unroll
        for (int ct = 0; ct < 8; ++ct)
            acc[ct] = __builtin_amdgcn_mfma_f32_16x16x32_bf16(afr, bfr[cur][ct], acc[ct], 0, 0, 0);
        afr = afr_nxt;
    }

    // ---- epilogue (C layout: col = ct*16 + lrow, row = wrow0 + lg*4 + reg)
    if (!FINAL) {
        #pragma unroll
        for (int ct = 0; ct < 8; ++ct) {
            int c = ct * 16 + lrow;
            float bv = bias[c];
            #pragma unroll
            for (int r = 0; r < 4; ++r) {
                int orow = wrow0 + lg * 4 + r;
                if (orow < M) hout[(size_t)orow * 128 + c] = f2bf(acc[ct][r] + bv);
            }
        }
    } else {
        float d0[4] = {0.f, 0.f, 0.f, 0.f};
        float d1[4] = {0.f, 0.f, 0.f, 0.f};
        #pragma unroll
        for (int ct = 0; ct < 8; ++ct) {
            int c = ct * 16 + lrow;
            float bv = bias[c];
            float wq0 = Wq[c];
            float wq1 = Wq[128 + c];
            #pragma unroll
            for (int r = 0; r < 4; ++r) {
                int orow = wrow0 + lg * 4 + r;
                float val = (orow < M) ? (acc[ct][r] + bv) : 0.f;
                d0[r] += val * wq0;
                d1[r] += val * wq1;
            }
        }
        #pragma unroll
        for (int r = 0; r < 4; ++r) {
            d0[r] += __shfl_xor(d0[r], 1); d0[r] += __shfl_xor(d0[r], 2);
            d0[r] += __shfl_xor(d0[r], 4); d0[r] += __shfl_xor(d0[r], 8);
            d1[r] += __shfl_xor(d1[r], 1); d1[r] += __shfl_xor(d1[r], 2);
            d1[r] += __shfl_xor(d1[r], 4); d1[r] += __shfl_xor(d1[r], 8);
        }
        if (lrow == 0) {
            #pragma unroll
            for (int r = 0; r < 4; ++r) {
                int orow = wrow0 + lg * 4 + r;
                if (orow < M) dotout[orow] = d1[r];
            }
        }
        float tot = d0[0] + d0[1] + d0[2] + d0[3];
        tot += __shfl_xor(tot, 16);
        tot += __shfl_xor(tot, 32);
        if (lane == 0) red[w] = tot;
        __syncthreads();
        if (t == 0) atomicAdd(S, red[0] + red[1] + red[2] + red[3]);
    }
}

// ---------------------------------------------------------------- out[i] = dot1[i] + S + bq
__global__ __launch_bounds__(256) void addout_kernel(
    float* __restrict__ outp, const float* __restrict__ S,
    const float* __restrict__ bq, int n)
{
    int i = blockIdx.x * 256 + threadIdx.x;
    if (i < n) outp[i] = outp[i] + S[0] + bq[0];
}

extern "C" void kernel_launch(void* const* d_in, const int* in_sizes, int n_in,
                              void* d_out, int out_size, void* d_ws, size_t ws_size,
                              hipStream_t stream)
{
    const float* x    = (const float*)d_in[0];
    const int*   vci  = (const int*)  d_in[1];   // NV x 8,  values < NC
    const int*   cvi  = (const int*)  d_in[2];   // NC x 16, values < NV
    const float* Wiv  = (const float*)d_in[3];
    const float* biv  = (const float*)d_in[4];
    const float* Wic  = (const float*)d_in[5];
    const float* bic  = (const float*)d_in[6];
    const float* Wvar = (const float*)d_in[7];
    const float* bvar = (const float*)d_in[8];
    const float* Wcon = (const float*)d_in[9];
    const float* bcon = (const float*)d_in[10];
    const float* Wq   = (const float*)d_in[11];
    const float* bq   = (const float*)d_in[12];
    float* outp = (float*)d_out;

    unsigned short* us = (unsigned short*)d_ws;
    size_t o = 0;
    unsigned short* vA    = us + o; o += (size_t)NV * 128;   // v0, then v1 in-place
    unsigned short* cA    = us + o; o += (size_t)NC * 128;   // c0
    unsigned short* cB    = us + o; o += (size_t)NC * 128;   // c1
    unsigned short* aggV  = us + o; o += (size_t)NV * 128;   // agg for v-layers
    unsigned short* aggC  = us + o; o += (size_t)NC * 128;   // agg for c-layer
    unsigned short* WbVar = us + o; o += 9 * 128 * 32;
    unsigned short* WbCon = us + o; o += 9 * 128 * 32;
    unsigned short* WbIv  = us + o; o += 128 * 32;
    unsigned short* WbIc  = us + o; o += 128 * 32;
    float* S = (float*)(us + o);

    const float* xc = x + (size_t)NV * 32;

    // weight pack + S zero
    pack_kernel<<<144, 256, 0, stream>>>(Wvar, Wcon, Wiv, Wic, WbVar, WbCon, WbIv, WbIc, S);
    // init
    init_mfma<<<(NV + 63) / 64, 256, 0, stream>>>(x,  WbIv, biv, vA, NV);
    init_mfma<<<(NC + 63) / 64, 256, 0, stream>>>(xc, WbIc, bic, cA, NC);

    // layer 1 aggregations
    agg_bf16<DCON><<<(NC * 16 + 255) / 256, 256, 0, stream>>>(vA, cvi, aggC, NC);
    agg_bf16<DVAR><<<(NV * 16 + 255) / 256, 256, 0, stream>>>(cA, vci, aggV, NV);
    // c1 = f(aggC, c0, xc)
    gemm_mfma<false><<<(NC + 63) / 64, 256, 0, stream>>>(
        cA, aggC, xc, WbCon, bcon, cB, nullptr, nullptr, nullptr, NC);
    // v1 = f(aggV, v0, xv)  [in-place: blocks stage only their own rows before writing]
    gemm_mfma<false><<<(NV + 63) / 64, 256, 0, stream>>>(
        vA, aggV, x, WbVar, bvar, vA, nullptr, nullptr, nullptr, NV);

    // layer 2: agg over c1, then v2-GEMM fused with readout (c2 dead)
    agg_bf16<DVAR><<<(NV * 16 + 255) / 256, 256, 0, stream>>>(cB, vci, aggV, NV);
    gemm_mfma<true><<<(NV + 63) / 64, 256, 0, stream>>>(
        vA, aggV, x, WbVar, bvar, nullptr, Wq, S, outp, NV);

    // out[i] = dot1[i] + (g·Wq[:128]) + bq
    addout_kernel<<<(NV + 255) / 256, 256, 0, stream>>>(outp, S, bq, NV);
}

// Round 9
// 274.046 us; speedup vs baseline: 1.0887x; 1.0887x over previous
//
#include <hip/hip_runtime.h>

#define NV 100000
#define NC 50000
#define DVAR 8
#define DCON 16

using short8 = __attribute__((ext_vector_type(8))) short;
using f32x4  = __attribute__((ext_vector_type(4))) float;

__device__ __forceinline__ unsigned short f2bf(float f) {
    union { float f; unsigned int u; } v; v.f = f;
    return (unsigned short)((v.u + 0x7fffu + ((v.u >> 16) & 1u)) >> 16);  // RNE
}
__device__ __forceinline__ float bflo(unsigned int u) {
    union { unsigned int u; float f; } v; v.u = u << 16; return v.f;
}
__device__ __forceinline__ float bfhi(unsigned int u) {
    union { unsigned int u; float f; } v; v.u = u & 0xffff0000u; return v.f;
}

// ---------------------------------------------------------------- pack W into MFMA B-fragment
__global__ __launch_bounds__(256) void pack_kernel(
    const float* __restrict__ Wvar, const float* __restrict__ Wcon,
    const float* __restrict__ Wiv,  const float* __restrict__ Wic,
    unsigned short* __restrict__ WbVar, unsigned short* __restrict__ WbCon,
    unsigned short* __restrict__ WbIv,  unsigned short* __restrict__ WbIc,
    float* __restrict__ S)
{
    const int tid = blockIdx.x * 256 + threadIdx.x;
    for (int i = tid; i < 9 * 128 * 32; i += gridDim.x * 256) {
        int s = i >> 12, rem = i & 4095, c = rem >> 5, k = rem & 31;
        int src = (s * 32 + k) * 128 + c;
        WbVar[i] = f2bf(Wvar[src]);
        WbCon[i] = f2bf(Wcon[src]);
    }
    for (int i = tid; i < 128 * 32; i += gridDim.x * 256) {
        int c = i >> 5, k = i & 31;
        int src = k * 128 + c;
        WbIv[i] = f2bf(Wiv[src]);
        WbIc[i] = f2bf(Wic[src]);
    }
    if (tid == 0) S[0] = 0.f;
}

// ---------------------------------------------------------------- init: h = bf16(x) @ W + b
__global__ __launch_bounds__(256) void init_mfma(
    const float* __restrict__ x,          // M x 32 (pre-offset)
    const unsigned short* __restrict__ Wb,
    const float* __restrict__ bias,
    unsigned short* __restrict__ hout, int M)
{
    const int t = threadIdx.x;
    const int lane = t & 63;
    const int w = t >> 6;
    const int lrow = lane & 15;
    const int lg = lane >> 4;
    const int wrow0 = blockIdx.x * 64 + w * 16;
    int arow = wrow0 + lrow;
    int arowc = arow < M ? arow : M - 1;

    const float4* xp = (const float4*)(x + (size_t)arowc * 32 + lg * 8);
    float4 xa = xp[0], xb = xp[1];
    short8 afr;
    afr[0] = (short)f2bf(xa.x); afr[1] = (short)f2bf(xa.y);
    afr[2] = (short)f2bf(xa.z); afr[3] = (short)f2bf(xa.w);
    afr[4] = (short)f2bf(xb.x); afr[5] = (short)f2bf(xb.y);
    afr[6] = (short)f2bf(xb.z); afr[7] = (short)f2bf(xb.w);

    #pragma unroll
    for (int ct = 0; ct < 8; ++ct) {
        int c = ct * 16 + lrow;
        short8 bfr = *(const short8*)(Wb + (size_t)c * 32 + lg * 8);
        f32x4 acc = {0.f, 0.f, 0.f, 0.f};
        acc = __builtin_amdgcn_mfma_f32_16x16x32_bf16(afr, bfr, acc, 0, 0, 0);
        float bv = bias[c];
        #pragma unroll
        for (int r = 0; r < 4; ++r) {
            int orow = wrow0 + lg * 4 + r;
            if (orow < M) hout[(size_t)orow * 128 + c] = f2bf(acc[r] + bv);
        }
    }
}

// ---------------------------------------------------------------- gather-sum (bf16, coalesced)
template<int DEG>
__global__ __launch_bounds__(256) void agg_bf16(
    const unsigned short* __restrict__ hnb, const int* __restrict__ idx,
    unsigned short* __restrict__ agg, int M)
{
    const int tid = blockIdx.x * 256 + threadIdx.x;
    const int row = tid >> 4;
    const int part = tid & 15;
    if (row >= M) return;
    int nb[DEG];
    #pragma unroll
    for (int d4 = 0; d4 < DEG / 4; ++d4)
        *(int4*)(&nb[d4 * 4]) = *(const int4*)(idx + (size_t)row * DEG + d4 * 4);
    float a0=0.f,a1=0.f,a2=0.f,a3=0.f,a4=0.f,a5=0.f,a6=0.f,a7=0.f;
    #pragma unroll
    for (int b = 0; b < DEG; b += 8) {
        uint4 q[8];
        #pragma unroll
        for (int j = 0; j < 8; ++j)
            q[j] = *(const uint4*)(hnb + (size_t)nb[b + j] * 128 + part * 8);
        #pragma unroll
        for (int j = 0; j < 8; ++j) {
            a0 += bflo(q[j].x); a1 += bfhi(q[j].x);
            a2 += bflo(q[j].y); a3 += bfhi(q[j].y);
            a4 += bflo(q[j].z); a5 += bfhi(q[j].z);
            a6 += bflo(q[j].w); a7 += bfhi(q[j].w);
        }
    }
    uint4 o;
    o.x = (unsigned)f2bf(a0) | ((unsigned)f2bf(a1) << 16);
    o.y = (unsigned)f2bf(a2) | ((unsigned)f2bf(a3) << 16);
    o.z = (unsigned)f2bf(a4) | ((unsigned)f2bf(a5) << 16);
    o.w = (unsigned)f2bf(a6) | ((unsigned)f2bf(a7) << 16);
    *(uint4*)(agg + (size_t)row * 128 + part * 8) = o;
}

// ---------------------------------------------------------------- fat-wave MFMA layer:
// h_out = [agg | h_self | x_self] @ W + b   (K = 288; x-step first, then 8 dbuf'd steps)
// Wave owns 64 rows (4 row-tiles): each B fragment loads once, feeds 4 MFMAs.
// FINAL: emit dot1[row] = h·Wq[128:] per row and atomicAdd S += Σ h·Wq[:128].
template<bool FINAL>
__global__ __launch_bounds__(256, 2) void gemm_mfma(
    const unsigned short* hself,      // may alias hout (in-place v-update)
    const unsigned short* __restrict__ aggin,
    const float* __restrict__ xself,
    const unsigned short* __restrict__ Wb,
    const float* __restrict__ bias,
    unsigned short* hout,
    const float* __restrict__ Wq, float* __restrict__ S, float* __restrict__ dotout,
    int M)
{
    __shared__ float red[4];
    const int t = threadIdx.x;
    const int lane = t & 63;
    const int w = t >> 6;
    const int lrow = lane & 15;
    const int lg = lane >> 4;
    const int wrow0 = blockIdx.x * 256 + w * 64;   // wave: rows [wrow0, wrow0+64)

    int arc[4];
    #pragma unroll
    for (int rt = 0; rt < 4; ++rt) {
        int r = wrow0 + rt * 16 + lrow;
        arc[rt] = r < M ? r : M - 1;
    }

    auto loadB = [&](short8* dst, int s) {
        #pragma unroll
        for (int ct = 0; ct < 8; ++ct)
            dst[ct] = *(const short8*)(Wb + ((size_t)s * 128 + ct * 16 + lrow) * 32 + lg * 8);
    };
    auto loadA = [&](short8* dst, int s) {   // s in 0..7: 0-3 = agg, 4-7 = self
        const unsigned short* src = (s < 4) ? aggin : hself;
        const int off = (s & 3) * 32 + lg * 8;
        #pragma unroll
        for (int rt = 0; rt < 4; ++rt)
            dst[rt] = *(const short8*)(src + (size_t)arc[rt] * 128 + off);
    };

    f32x4 acc[4][8];
    short8 bA[8], bB[8], aA[4], aB[4];

    // x-step (s=8) first: transient fp32 regs die early
    loadB(bA, 8);
    loadB(bB, 0); loadA(aB, 0);
    {
        short8 xfr[4];
        #pragma unroll
        for (int rt = 0; rt < 4; ++rt) {
            const float4* xp = (const float4*)(xself + (size_t)arc[rt] * 32 + lg * 8);
            float4 xa = xp[0], xb = xp[1];
            xfr[rt][0] = (short)f2bf(xa.x); xfr[rt][1] = (short)f2bf(xa.y);
            xfr[rt][2] = (short)f2bf(xa.z); xfr[rt][3] = (short)f2bf(xa.w);
            xfr[rt][4] = (short)f2bf(xb.x); xfr[rt][5] = (short)f2bf(xb.y);
            xfr[rt][6] = (short)f2bf(xb.z); xfr[rt][7] = (short)f2bf(xb.w);
        }
        #pragma unroll
        for (int ct = 0; ct < 8; ++ct)
            #pragma unroll
            for (int rt = 0; rt < 4; ++rt)
                acc[rt][ct] = __builtin_amdgcn_mfma_f32_16x16x32_bf16(
                    xfr[rt], bA[ct], (f32x4){0.f, 0.f, 0.f, 0.f}, 0, 0, 0);
    }

    // steps s=0..7, named double buffers, compile-time phase after unroll
    #pragma unroll
    for (int k = 0; k < 8; ++k) {
        if ((k & 1) == 0) {
            if (k < 7) { loadB(bA, k + 1); loadA(aA, k + 1); }
            #pragma unroll
            for (int ct = 0; ct < 8; ++ct)
                #pragma unroll
                for (int rt = 0; rt < 4; ++rt)
                    acc[rt][ct] = __builtin_amdgcn_mfma_f32_16x16x32_bf16(
                        aB[rt], bB[ct], acc[rt][ct], 0, 0, 0);
        } else {
            if (k < 7) { loadB(bB, k + 1); loadA(aB, k + 1); }
            #pragma unroll
            for (int ct = 0; ct < 8; ++ct)
                #pragma unroll
                for (int rt = 0; rt < 4; ++rt)
                    acc[rt][ct] = __builtin_amdgcn_mfma_f32_16x16x32_bf16(
                        aA[rt], bA[ct], acc[rt][ct], 0, 0, 0);
        }
    }

    // ---- epilogue (C layout: col = ct*16 + lrow, row = wrow0 + rt*16 + lg*4 + reg)
    if (!FINAL) {
        #pragma unroll
        for (int rt = 0; rt < 4; ++rt)
            #pragma unroll
            for (int ct = 0; ct < 8; ++ct) {
                int c = ct * 16 + lrow;
                float bv = bias[c];
                #pragma unroll
                for (int r = 0; r < 4; ++r) {
                    int orow = wrow0 + rt * 16 + lg * 4 + r;
                    if (orow < M) hout[(size_t)orow * 128 + c] = f2bf(acc[rt][ct][r] + bv);
                }
            }
    } else {
        float tot = 0.f;
        #pragma unroll
        for (int rt = 0; rt < 4; ++rt) {
            float d0[4] = {0.f, 0.f, 0.f, 0.f};
            float d1[4] = {0.f, 0.f, 0.f, 0.f};
            #pragma unroll
            for (int ct = 0; ct < 8; ++ct) {
                int c = ct * 16 + lrow;
                float bv = bias[c];
                float wq0 = Wq[c];
                float wq1 = Wq[128 + c];
                #pragma unroll
                for (int r = 0; r < 4; ++r) {
                    int orow = wrow0 + rt * 16 + lg * 4 + r;
                    float val = (orow < M) ? (acc[rt][ct][r] + bv) : 0.f;
                    d0[r] += val * wq0;
                    d1[r] += val * wq1;
                }
            }
            #pragma unroll
            for (int r = 0; r < 4; ++r) {
                d0[r] += __shfl_xor(d0[r], 1); d0[r] += __shfl_xor(d0[r], 2);
                d0[r] += __shfl_xor(d0[r], 4); d0[r] += __shfl_xor(d0[r], 8);
                d1[r] += __shfl_xor(d1[r], 1); d1[r] += __shfl_xor(d1[r], 2);
                d1[r] += __shfl_xor(d1[r], 4); d1[r] += __shfl_xor(d1[r], 8);
            }
            if (lrow == 0) {
                #pragma unroll
                for (int r = 0; r < 4; ++r) {
                    int orow = wrow0 + rt * 16 + lg * 4 + r;
                    if (orow < M) dotout[orow] = d1[r];
                }
            }
            tot += d0[0] + d0[1] + d0[2] + d0[3];
        }
        tot += __shfl_xor(tot, 16);
        tot += __shfl_xor(tot, 32);
        if (lane == 0) red[w] = tot;
        __syncthreads();
        if (t == 0) atomicAdd(S, red[0] + red[1] + red[2] + red[3]);
    }
}

// ---------------------------------------------------------------- out[i] = dot1[i] + S + bq
__global__ __launch_bounds__(256) void addout_kernel(
    float* __restrict__ outp, const float* __restrict__ S,
    const float* __restrict__ bq, int n)
{
    int i = blockIdx.x * 256 + threadIdx.x;
    if (i < n) outp[i] = outp[i] + S[0] + bq[0];
}

extern "C" void kernel_launch(void* const* d_in, const int* in_sizes, int n_in,
                              void* d_out, int out_size, void* d_ws, size_t ws_size,
                              hipStream_t stream)
{
    const float* x    = (const float*)d_in[0];
    const int*   vci  = (const int*)  d_in[1];   // NV x 8,  values < NC
    const int*   cvi  = (const int*)  d_in[2];   // NC x 16, values < NV
    const float* Wiv  = (const float*)d_in[3];
    const float* biv  = (const float*)d_in[4];
    const float* Wic  = (const float*)d_in[5];
    const float* bic  = (const float*)d_in[6];
    const float* Wvar = (const float*)d_in[7];
    const float* bvar = (const float*)d_in[8];
    const float* Wcon = (const float*)d_in[9];
    const float* bcon = (const float*)d_in[10];
    const float* Wq   = (const float*)d_in[11];
    const float* bq   = (const float*)d_in[12];
    float* outp = (float*)d_out;

    unsigned short* us = (unsigned short*)d_ws;
    size_t o = 0;
    unsigned short* vA    = us + o; o += (size_t)NV * 128;   // v0, then v1 in-place
    unsigned short* cA    = us + o; o += (size_t)NC * 128;   // c0
    unsigned short* cB    = us + o; o += (size_t)NC * 128;   // c1
    unsigned short* aggV  = us + o; o += (size_t)NV * 128;   // agg for v-layers
    unsigned short* aggC  = us + o; o += (size_t)NC * 128;   // agg for c-layer
    unsigned short* WbVar = us + o; o += 9 * 128 * 32;
    unsigned short* WbCon = us + o; o += 9 * 128 * 32;
    unsigned short* WbIv  = us + o; o += 128 * 32;
    unsigned short* WbIc  = us + o; o += 128 * 32;
    float* S = (float*)(us + o);

    const float* xc = x + (size_t)NV * 32;

    // weight pack + S zero
    pack_kernel<<<144, 256, 0, stream>>>(Wvar, Wcon, Wiv, Wic, WbVar, WbCon, WbIv, WbIc, S);
    // init
    init_mfma<<<(NV + 63) / 64, 256, 0, stream>>>(x,  WbIv, biv, vA, NV);
    init_mfma<<<(NC + 63) / 64, 256, 0, stream>>>(xc, WbIc, bic, cA, NC);

    // layer 1 aggregations
    agg_bf16<DCON><<<(NC * 16 + 255) / 256, 256, 0, stream>>>(vA, cvi, aggC, NC);
    agg_bf16<DVAR><<<(NV * 16 + 255) / 256, 256, 0, stream>>>(cA, vci, aggV, NV);
    // c1 = f(aggC, c0, xc)
    gemm_mfma<false><<<(NC + 255) / 256, 256, 0, stream>>>(
        cA, aggC, xc, WbCon, bcon, cB, nullptr, nullptr, nullptr, NC);
    // v1 = f(aggV, v0, xv)  [in-place: waves read only their own rows before writing]
    gemm_mfma<false><<<(NV + 255) / 256, 256, 0, stream>>>(
        vA, aggV, x, WbVar, bvar, vA, nullptr, nullptr, nullptr, NV);

    // layer 2: agg over c1, then v2-GEMM fused with readout (c2 dead)
    agg_bf16<DVAR><<<(NV * 16 + 255) / 256, 256, 0, stream>>>(cB, vci, aggV, NV);
    gemm_mfma<true><<<(NV + 255) / 256, 256, 0, stream>>>(
        vA, aggV, x, WbVar, bvar, nullptr, Wq, S, outp, NV);

    // out[i] = dot1[i] + (g·Wq[:128]) + bq
    addout_kernel<<<(NV + 255) / 256, 256, 0, stream>>>(outp, S, bq, NV);
}